// Round 14
// baseline (791.771 us; speedup 1.0000x reference)
//
#include <hip/hip_runtime.h>
#include <hip/hip_bf16.h>
#include <stdint.h>

#define TTOK 2048
#define DDIM 2048
#define IDIM 5632
#define NEXP 8

typedef __attribute__((ext_vector_type(8))) short bf16x8;
typedef __attribute__((ext_vector_type(4))) float f32x4;
typedef __attribute__((ext_vector_type(8))) unsigned short u16x8;
typedef __attribute__((ext_vector_type(4))) unsigned short u16x4;

__device__ __forceinline__ unsigned short f2bf(float f) {
  union { float f; uint32_t u; } v; v.f = f;
  uint32_t u = v.u + 0x7fffu + ((v.u >> 16) & 1u);
  return (unsigned short)(u >> 16);
}

__device__ __forceinline__ uint32_t fbits(float f) {
  union { float f; uint32_t u; } v; v.f = f; return v.u;
}

// truncating packed f32x2 -> bf16x2 via v_perm_b32 (1 inst per 2 values)
__device__ __forceinline__ u16x8 cvt8t(float4 a, float4 b) {
  union { u16x8 v; uint32_t w[4]; } r;
  r.w[0] = __builtin_amdgcn_perm(fbits(a.y), fbits(a.x), 0x07060302);
  r.w[1] = __builtin_amdgcn_perm(fbits(a.w), fbits(a.z), 0x07060302);
  r.w[2] = __builtin_amdgcn_perm(fbits(b.y), fbits(b.x), 0x07060302);
  r.w[3] = __builtin_amdgcn_perm(fbits(b.w), fbits(b.z), 0x07060302);
  return r.v;
}

typedef __attribute__((address_space(3))) void lds_t;
typedef const __attribute__((address_space(1))) void gbl_t;
__device__ __forceinline__ void gload16(const void* g, void* l) {
  __builtin_amdgcn_global_load_lds((gbl_t*)g, (lds_t*)l, 16, 0, 0);
}

// gateup barrier: retire the 2 A-gloads of this iter, keep the 4 B reg-loads in flight
#define GU_BAR() asm volatile("s_waitcnt vmcnt(4) lgkmcnt(0)\n\ts_barrier" ::: "memory")
// down barrier: drain everything (gloads issued before the MFMA phase; 4 blocks/CU cover)
#define DN_BAR() asm volatile("s_waitcnt vmcnt(0) lgkmcnt(0)\n\ts_barrier" ::: "memory")

// ---------------- router: logits, top-2, softmax, expert lists, x->bf16 ----------------
__global__ __launch_bounds__(256) void router_kernel(
    const float* __restrict__ x, const float* __restrict__ gw,
    unsigned short* __restrict__ xbf,
    int* __restrict__ cnt, int* __restrict__ slots, float* __restrict__ wts)
{
  const int lane = threadIdx.x & 63;
  const int t = (blockIdx.x * blockDim.x + threadIdx.x) >> 6;
  const float* xr = x + (size_t)t * DDIM;
  float acc[NEXP];
#pragma unroll
  for (int e = 0; e < NEXP; ++e) acc[e] = 0.f;
#pragma unroll
  for (int it = 0; it < DDIM / 256; ++it) {
    const int d = (it * 64 + lane) * 4;
    const float4 xv = *(const float4*)(xr + d);
    u16x4 xb; xb[0]=f2bf(xv.x); xb[1]=f2bf(xv.y); xb[2]=f2bf(xv.z); xb[3]=f2bf(xv.w);
    *(u16x4*)(xbf + (size_t)t * DDIM + d) = xb;
#pragma unroll
    for (int e = 0; e < NEXP; ++e) {
      const float4 gv = *(const float4*)(gw + (size_t)e * DDIM + d);
      acc[e] += xv.x*gv.x + xv.y*gv.y + xv.z*gv.z + xv.w*gv.w;
    }
  }
#pragma unroll
  for (int e = 0; e < NEXP; ++e) {
    float v = acc[e];
#pragma unroll
    for (int off = 32; off > 0; off >>= 1) v += __shfl_xor(v, off);
    acc[e] = v;
  }
  if (lane == 0) {
    int i0 = 0; float v0 = acc[0];
#pragma unroll
    for (int e = 1; e < NEXP; ++e) if (acc[e] > v0) { v0 = acc[e]; i0 = e; }
    int i1 = -1; float v1 = -3.4e38f;
#pragma unroll
    for (int e = 0; e < NEXP; ++e) { if (e == i0) continue; if (acc[e] > v1) { v1 = acc[e]; i1 = e; } }
    const float e1 = __expf(v1 - v0);
    const float w0 = 1.f / (1.f + e1);
    const float w1 = e1 / (1.f + e1);
    const int p0 = atomicAdd(&cnt[i0], 1);
    slots[i0 * TTOK + p0] = t * 2;     wts[i0 * TTOK + p0] = w0;
    const int p1 = atomicAdd(&cnt[i1], 1);
    slots[i1 * TTOK + p1] = t * 2 + 1; wts[i1 * TTOK + p1] = w1;
  }
}

// ---------------- plan: compact (expert, mt) tile list, BM=128 ----------------
__global__ void plan_kernel(const int* __restrict__ cnt,
                            int* __restrict__ tilemap, int* __restrict__ ntiles)
{
  if (threadIdx.x == 0 && blockIdx.x == 0) {
    int n = 0;
#pragma unroll
    for (int e = 0; e < NEXP; ++e) {
      const int nt = (cnt[e] + 127) >> 7;
      for (int m = 0; m < nt; ++m) tilemap[n++] = (e << 8) | m;
    }
    ntiles[0] = n;   // <= 39
  }
}

// A/B chunk swizzle (BK=32, 4 chunks/row): chunk c of row r stored at c ^ (r & 3)
// down-B fp32 (8 chunks/row): chunk c of row r stored at c ^ (r & 7)

// ---- gate+up: 128M x (64g+64u), BK=32, 4 waves joint-mat 2x2 grid, 3 blocks/CU ----
__global__ __launch_bounds__(256, 3) void gateup_kernel(
    const unsigned short* __restrict__ xbf,
    const float* __restrict__ wg, const float* __restrict__ wu,
    const int* __restrict__ cnt, const int* __restrict__ slots,
    const int* __restrict__ tilemap, const int* __restrict__ ntiles,
    unsigned short* __restrict__ h)
{
  // grid 3520 = 40 slots x 88 panels; XCD swizzle q=440, tile fastest
  const int flat = (blockIdx.x & 7) * 440 + (blockIdx.x >> 3);
  const int ti = flat % 40;
  if (ti >= ntiles[0]) return;
  const int em = tilemap[ti];
  const int e = em >> 8;
  const int mt = em & 255;
  const int n0 = (flat / 40) * 64;
  const int count = cnt[e];
  const int m0 = mt * 128;

  __shared__ unsigned short A[2][128][32];    // 16 KB
  __shared__ unsigned short Bg[2][64][32];    // 8 KB
  __shared__ unsigned short Bu[2][64][32];    // 8 KB
  __shared__ int rslot[128];
  __shared__ int rtok[128];

  const int tid = threadIdx.x;
  const int lane = tid & 63;
  const int wid = tid >> 6;           // 0..3

  if (tid < 128) {
    const int idx = m0 + tid;
    const int safe = slots[e * TTOK + m0];
    const int s = (idx < count) ? slots[e * TTOK + idx] : safe;
    rslot[tid] = (idx < count) ? s : -1;
    rtok[tid] = s >> 1;
  }
  __syncthreads();

  // A gather: 2 gloads/wave; lane l -> row grp+(l>>2), slot l&3, src chunk (l&3)^(row&3)
  const unsigned short* aptr[2];
#pragma unroll
  for (int j = 0; j < 2; ++j) {
    const int arow = wid * 32 + j * 16 + (lane >> 2);
    aptr[j] = xbf + (size_t)rtok[arow] * DDIM + (((lane & 3) ^ (arow & 3)) * 8);
  }

  // B staging: 64 rows, 4 thr/row; thread owns logical chunk lc (8 fp32 -> 8 bf16)
  const int brow = tid >> 2;
  const int lc = tid & 3;
  const int bslot = lc ^ (brow & 3);
  const size_t wo = (size_t)e * IDIM * DDIM + (size_t)(n0 + brow) * DDIM + lc * 8;
  const float* gsrc = wg + wo;
  const float* usrc = wu + wo;

  // wave roles: 2x2 grid over (M-half, N-half); each wave computes BOTH g and u
  const int wr = wid >> 1, wc = wid & 1;
  const int fr = lane & 15;
  const int kc = lane >> 4;           // chunk 0..3

  f32x4 accg[4][2] = {};
  f32x4 accu[4][2] = {};

  float4 Pg[2], Pu[2];
  // prologue: A(0)->buf0; B(0)->regs->buf0; B(1)->regs; publish
  gload16(aptr[0], &A[0][wid * 32][0]);
  gload16(aptr[1], &A[0][wid * 32 + 16][0]);
  Pg[0] = *(const float4*)(gsrc);     Pg[1] = *(const float4*)(gsrc + 4);
  Pu[0] = *(const float4*)(usrc);     Pu[1] = *(const float4*)(usrc + 4);
  *(u16x8*)&Bg[0][brow][bslot * 8] = cvt8t(Pg[0], Pg[1]);
  *(u16x8*)&Bu[0][brow][bslot * 8] = cvt8t(Pu[0], Pu[1]);
  Pg[0] = *(const float4*)(gsrc + 32); Pg[1] = *(const float4*)(gsrc + 36);
  Pu[0] = *(const float4*)(usrc + 32); Pu[1] = *(const float4*)(usrc + 36);
  GU_BAR();

#pragma unroll 2
  for (int t = 0; t < 64; ++t) {
    const int cur = t & 1;
    const int kpA = ((t + 1 < 64) ? t + 1 : 63) * 32;
    const int kpB = ((t + 2 < 64) ? t + 2 : 63) * 32;

    // 1) A(t+1) -> bufA[cur^1] (oldest vmem of this iter)
    gload16(aptr[0] + kpA, &A[cur ^ 1][wid * 32][0]);
    gload16(aptr[1] + kpA, &A[cur ^ 1][wid * 32 + 16][0]);
    __builtin_amdgcn_sched_barrier(0);
    // 2) cvt + ds_write B(t+1) (P loaded last iter; compiler waits its counted vmcnt)
    *(u16x8*)&Bg[cur ^ 1][brow][bslot * 8] = cvt8t(Pg[0], Pg[1]);
    *(u16x8*)&Bu[cur ^ 1][brow][bslot * 8] = cvt8t(Pu[0], Pu[1]);
    // 3) B(t+2) -> regs
    Pg[0] = *(const float4*)(gsrc + kpB);     Pg[1] = *(const float4*)(gsrc + kpB + 4);
    Pu[0] = *(const float4*)(usrc + kpB);     Pu[1] = *(const float4*)(usrc + kpB + 4);
    __builtin_amdgcn_sched_barrier(0);

    // 4) MFMA on buf[cur]: 16 MFMAs, A amp 2 / B amp 2
    __builtin_amdgcn_s_setprio(1);
    bf16x8 a[4], bg[2], bu[2];
#pragma unroll
    for (int mf = 0; mf < 4; ++mf) {
      const int r = wr * 64 + mf * 16 + fr;
      a[mf] = *(const bf16x8*)&A[cur][r][(kc ^ (r & 3)) * 8];
    }
#pragma unroll
    for (int nf = 0; nf < 2; ++nf) {
      const int rb = wc * 32 + nf * 16 + fr;
      bg[nf] = *(const bf16x8*)&Bg[cur][rb][(kc ^ (rb & 3)) * 8];
      bu[nf] = *(const bf16x8*)&Bu[cur][rb][(kc ^ (rb & 3)) * 8];
    }
#pragma unroll
    for (int mf = 0; mf < 4; ++mf)
#pragma unroll
      for (int nf = 0; nf < 2; ++nf) {
        accg[mf][nf] = __builtin_amdgcn_mfma_f32_16x16x32_bf16(a[mf], bg[nf], accg[mf][nf], 0, 0, 0);
        accu[mf][nf] = __builtin_amdgcn_mfma_f32_16x16x32_bf16(a[mf], bu[nf], accu[mf][nf], 0, 0, 0);
      }
    __builtin_amdgcn_s_setprio(0);

    // 5) publish buf[cur^1]: A(t+1) retired, P(t+2) stays in flight
    GU_BAR();
  }

  // epilogue: SiLU is wave-local (g and u accumulated by the same wave)
#pragma unroll
  for (int mf = 0; mf < 4; ++mf)
#pragma unroll
    for (int nf = 0; nf < 2; ++nf)
#pragma unroll
      for (int j = 0; j < 4; ++j) {
        const int r = wr * 64 + mf * 16 + (lane >> 4) * 4 + j;
        const int s = rslot[r];
        if (s >= 0) {
          const float g = accg[mf][nf][j];
          const float u = accu[mf][nf][j];
          const float hv = g / (1.f + __expf(-g)) * u;
          h[(size_t)s * IDIM + n0 + wc * 32 + nf * 16 + fr] = f2bf(hv);
        }
      }
}

// ---- down: 128M x 64N, BK=32, K-split x2, A+B via gload_lds, 4 blocks/CU ----
__global__ __launch_bounds__(256, 4) void down_kernel(
    const unsigned short* __restrict__ h,
    const float* __restrict__ wd,
    const int* __restrict__ cnt, const int* __restrict__ slots,
    const float* __restrict__ wts,
    const int* __restrict__ tilemap, const int* __restrict__ ntiles,
    float* __restrict__ out)
{
  // grid 2560 = 40 slots x 32 panels x 2 ksplit; XCD swizzle q=320
  const int flat = (blockIdx.x & 7) * 320 + (blockIdx.x >> 3);
  const int ti = flat % 40;
  if (ti >= ntiles[0]) return;
  const int em = tilemap[ti];
  const int e = em >> 8;
  const int mt = em & 255;
  const int rest = flat / 40;          // 0..63
  const int n0 = (rest & 31) * 64;
  const int kbase = (rest >> 5) * (IDIM / 2);
  const int count = cnt[e];
  const int m0 = mt * 128;

  __shared__ unsigned short A[2][128][32];   // 16 KB bf16
  __shared__ float Bf[2][64][32];            // 16 KB fp32
  __shared__ int rslot[128];
  __shared__ float rw[128];

  const int tid = threadIdx.x;
  const int lane = tid & 63;
  const int wid = tid >> 6;

  if (tid < 128) {
    const int idx = m0 + tid;
    const int safe = slots[e * TTOK + m0];
    const int s = (idx < count) ? slots[e * TTOK + idx] : safe;
    rslot[tid] = (idx < count) ? s : (safe | 0x40000000);
    rw[tid] = (idx < count) ? wts[e * TTOK + idx] : 0.f;
  }
  __syncthreads();

  // A: gathered h rows; lane l -> row grp+(l>>2), slot l&3, src chunk (l&3)^(row&3)
  const unsigned short* aptr[2];
#pragma unroll
  for (int j = 0; j < 2; ++j) {
    const int arow = wid * 32 + j * 16 + (lane >> 2);
    aptr[j] = h + (size_t)(rslot[arow] & 0x3fffffff) * IDIM + kbase
              + (((lane & 3) ^ (arow & 3)) * 8);
  }

  // B: wd fp32 rows (128 B = 8 chunks); lane l -> row grp+(l>>3), slot l&7,
  // src chunk (l&7)^(row&7)
  const float* bptr[2];
#pragma unroll
  for (int j = 0; j < 2; ++j) {
    const int browg = wid * 16 + j * 8 + (lane >> 3);
    bptr[j] = wd + (size_t)e * DDIM * IDIM + (size_t)(n0 + browg) * IDIM + kbase
              + (((lane & 7) ^ (browg & 7)) * 4);
  }

  const int wr = wid >> 1, wc = wid & 1;
  const int fr = lane & 15;
  const int kc = lane >> 4;

  f32x4 acc[4][2] = {};

  // prologue: stage tile 0
  gload16(aptr[0], &A[0][wid * 32][0]);
  gload16(aptr[1], &A[0][wid * 32 + 16][0]);
  gload16(bptr[0], &Bf[0][wid * 16][0]);
  gload16(bptr[1], &Bf[0][wid * 16 + 8][0]);
  DN_BAR();

#pragma unroll 2
  for (int t = 0; t < 88; ++t) {
    const int cur = t & 1;
    if (t < 87) {
      const int kp = (t + 1) * 32;
      gload16(aptr[0] + kp, &A[cur ^ 1][wid * 32][0]);
      gload16(aptr[1] + kp, &A[cur ^ 1][wid * 32 + 16][0]);
      gload16(bptr[0] + kp, &Bf[cur ^ 1][wid * 16][0]);
      gload16(bptr[1] + kp, &Bf[cur ^ 1][wid * 16 + 8][0]);
    }
    __builtin_amdgcn_sched_barrier(0);

    __builtin_amdgcn_s_setprio(1);
    bf16x8 a[4], b[2];
#pragma unroll
    for (int mf = 0; mf < 4; ++mf) {
      const int r = wr * 64 + mf * 16 + fr;
      a[mf] = *(const bf16x8*)&A[cur][r][(kc ^ (r & 3)) * 8];
    }
#pragma unroll
    for (int nf = 0; nf < 2; ++nf) {
      const int rb = wc * 32 + nf * 16 + fr;
      const int c0 = kc * 2;
      const float4 fa = *(const float4*)&Bf[cur][rb][((c0)     ^ (rb & 7)) * 4];
      const float4 fb = *(const float4*)&Bf[cur][rb][((c0 + 1) ^ (rb & 7)) * 4];
      b[nf] = (bf16x8)cvt8t(fa, fb);
    }
#pragma unroll
    for (int mf = 0; mf < 4; ++mf)
#pragma unroll
      for (int nf = 0; nf < 2; ++nf)
        acc[mf][nf] = __builtin_amdgcn_mfma_f32_16x16x32_bf16(a[mf], b[nf], acc[mf][nf], 0, 0, 0);
    __builtin_amdgcn_s_setprio(0);

    DN_BAR();   // next-tile gloads drained (issued before MFMA; 4 blocks/CU cover)
  }

  // epilogue: weighted scatter-add
#pragma unroll
  for (int mf = 0; mf < 4; ++mf)
#pragma unroll
    for (int j = 0; j < 4; ++j) {
      const int r = wr * 64 + mf * 16 + (lane >> 4) * 4 + j;
      const int s = rslot[r];
      if (!(s & 0x40000000)) {
        const int t2 = s >> 1;
        const float w = rw[r];
#pragma unroll
        for (int nf = 0; nf < 2; ++nf)
          atomicAdd(out + (size_t)t2 * DDIM + n0 + wc * 32 + nf * 16 + fr,
                    acc[mf][nf][j] * w);
      }
    }
}

extern "C" void kernel_launch(void* const* d_in, const int* in_sizes, int n_in,
                              void* d_out, int out_size, void* d_ws, size_t ws_size,
                              hipStream_t stream) {
  const float* x  = (const float*)d_in[0];
  const float* gw = (const float*)d_in[1];
  const float* wg = (const float*)d_in[2];
  const float* wu = (const float*)d_in[3];
  const float* wd = (const float*)d_in[4];
  float* out = (float*)d_out;

  char* ws = (char*)d_ws;
  unsigned short* xbf = (unsigned short*)ws;                       // 8,388,608 B
  unsigned short* h   = (unsigned short*)(ws + 8388608);           // 46,137,344 B
  int*   slots = (int*)(ws + 8388608 + 46137344);                  // 65,536 B
  float* wts   = (float*)(ws + 8388608 + 46137344 + 65536);        // 65,536 B
  int*   cnt   = (int*)(ws + 8388608 + 46137344 + 131072);         // 32 B
  int*   tmap  = (int*)(ws + 8388608 + 46137344 + 131072 + 32);    // 256 B
  int*   ntl   = (int*)(ws + 8388608 + 46137344 + 131072 + 288);   // 4 B

  hipMemsetAsync(cnt, 0, NEXP * sizeof(int), stream);
  hipMemsetAsync(d_out, 0, (size_t)TTOK * DDIM * sizeof(float), stream);

  router_kernel<<<TTOK / 4, 256, 0, stream>>>(x, gw, xbf, cnt, slots, wts);
  plan_kernel<<<1, 64, 0, stream>>>(cnt, tmap, ntl);
  gateup_kernel<<<3520, 256, 0, stream>>>(xbf, wg, wu, cnt, slots, tmap, ntl, h);
  down_kernel<<<2560, 256, 0, stream>>>(h, wd, cnt, slots, wts, tmap, ntl, out);
}